// Round 1
// baseline (446.810 us; speedup 1.0000x reference)
//
#include <hip/hip_runtime.h>
#include <math.h>

// Dims (fixed by the problem)
constexpr int Bb = 2, Nn = 512, Tt = 12, Ee = 128, Hh = 8, Dd = 16;
constexpr int NTOK   = Bb * Nn * Tt;      // 12288 tokens
constexpr int PROJ   = NTOK * Ee;         // 1572864 floats per [B,N,T,E] tensor
constexpr int SLICES = Bb * Hh * Tt;      // 192 attention slices
constexpr int MT     = 32;                // tokens per GEMM block

// Workspace layout (floats):
//   proj[0..6]: Qf,Kf,Vf,Qs,Ks,Vs,Qfs  in head-major [B,H,T,N,D]  (7 * 6MB)
//   ctx[0..3] : attention outputs      in token-major [B,N,T,E]   (4 * 6MB)
// total ~69 MB

struct PtrPack { const float* x[6]; const float* W[6]; };

__device__ __forceinline__ void fma4(float4& a, float s, float4 w) {
  a.x = fmaf(s, w.x, a.x); a.y = fmaf(s, w.y, a.y);
  a.z = fmaf(s, w.z, a.z); a.w = fmaf(s, w.w, a.w);
}
__device__ __forceinline__ float dot4(float4 a, float4 b, float acc) {
  acc = fmaf(a.x, b.x, acc); acc = fmaf(a.y, b.y, acc);
  acc = fmaf(a.z, b.z, acc); acc = fmaf(a.w, b.w, acc);
  return acc;
}
__device__ __forceinline__ void scl4(float4& a, float s) {
  a.x *= s; a.y *= s; a.z *= s; a.w *= s;
}

// ---------------------------------------------------------------------------
// Kernel P: y = x @ W for 6 inputs; writes head-major [B,H,T,N,D].
// type 3 (Qs) additionally writes Qfs = Kj[n]*(Qs - Qs^2/(Vfp[n]+1e-5)).
// ---------------------------------------------------------------------------
__global__ __launch_bounds__(256) void proj_kernel(
    PtrPack pp, const float* __restrict__ Kj, const float* __restrict__ Vfp,
    float* __restrict__ proj)
{
  __shared__ float Ws[Ee * Ee];   // 64 KB
  __shared__ float Xs[MT * Ee];   // 16 KB
  const int ty  = blockIdx.y;           // which projection 0..5
  const int tid = threadIdx.x;
  const float* __restrict__ W = pp.W[ty];
  const float* __restrict__ x = pp.x[ty];
  const int tk0 = blockIdx.x * MT;

  for (int i = tid * 4; i < Ee * Ee; i += 1024)
    *(float4*)&Ws[i] = *(const float4*)&W[i];
  for (int i = tid * 4; i < MT * Ee; i += 1024)
    *(float4*)&Xs[i] = *(const float4*)&x[(size_t)tk0 * Ee + i];
  __syncthreads();

  const int c4 = (tid & 31) * 4;   // output col base (0..124)
  const int tg = tid >> 5;         // token group 0..7 -> 4 tokens each

  float4 acc[4];
  #pragma unroll
  for (int i = 0; i < 4; ++i) acc[i] = make_float4(0.f, 0.f, 0.f, 0.f);

  for (int k = 0; k < Ee; k += 4) {
    float4 w0 = *(const float4*)&Ws[(k + 0) * Ee + c4];
    float4 w1 = *(const float4*)&Ws[(k + 1) * Ee + c4];
    float4 w2 = *(const float4*)&Ws[(k + 2) * Ee + c4];
    float4 w3 = *(const float4*)&Ws[(k + 3) * Ee + c4];
    #pragma unroll
    for (int tt = 0; tt < 4; ++tt) {
      float4 xv = *(const float4*)&Xs[(tg * 4 + tt) * Ee + k];
      fma4(acc[tt], xv.x, w0); fma4(acc[tt], xv.y, w1);
      fma4(acc[tt], xv.z, w2); fma4(acc[tt], xv.w, w3);
    }
  }

  const int h = c4 >> 4, d0 = c4 & 15;
  #pragma unroll
  for (int tt = 0; tt < 4; ++tt) {
    const int tk = tk0 + tg * 4 + tt;
    const int b  = tk / (Nn * Tt);
    const int rm = tk - b * (Nn * Tt);
    const int n  = rm / Tt;
    const int t  = rm - n * Tt;
    const size_t off = ((((size_t)b * Hh + h) * Tt + t) * Nn + n) * Dd + d0;
    *(float4*)&proj[(size_t)ty * PROJ + off] = acc[tt];
    if (ty == 3) {  // FlowSpeed nonlinearity -> Qfs (proj slot 6)
      const float kj  = Kj[n];
      const float inv = 1.0f / (Vfp[n] + 1e-5f);
      float4 q = acc[tt], g;
      g.x = kj * (q.x - q.x * q.x * inv);
      g.y = kj * (q.y - q.y * q.y * inv);
      g.z = kj * (q.z - q.z * q.z * inv);
      g.w = kj * (q.w - q.w * q.w * inv);
      *(float4*)&proj[(size_t)6 * PROJ + off] = g;
    }
  }
}

// ---------------------------------------------------------------------------
// Kernel A: flash attention per (slice, type). 256 threads, 2 q-rows each.
// Writes ctx in token-major [B,N,T,E] so kernel O is a plain GEMM.
// ---------------------------------------------------------------------------
__global__ __launch_bounds__(256) void attn_kernel(
    const float* __restrict__ proj, float* __restrict__ ctx)
{
  __shared__ float Ks_[Nn * Dd];  // 32 KB
  __shared__ float Vs_[Nn * Dd];  // 32 KB
  const int slice = blockIdx.x;   // (b*H+h)*T+t
  const int ty    = blockIdx.y;   // 0:ff 1:fs 2:sf 3:ss
  const int aidx[4] = {0, 1, 4, 3};
  const int bidx[4] = {1, 6, 0, 4};
  const int vidx[4] = {2, 2, 5, 5};
  const size_t base = (size_t)slice * (Nn * Dd);
  const float* __restrict__ Aq = proj + (size_t)aidx[ty] * PROJ + base;
  const float* __restrict__ Bk = proj + (size_t)bidx[ty] * PROJ + base;
  const float* __restrict__ Vv = proj + (size_t)vidx[ty] * PROJ + base;
  const int tid = threadIdx.x;

  for (int i = tid * 4; i < Nn * Dd; i += 1024) {
    *(float4*)&Ks_[i] = *(const float4*)&Bk[i];
    *(float4*)&Vs_[i] = *(const float4*)&Vv[i];
  }

  // scale = 1/sqrt(D); fold log2(e)*scale into q so p = exp2(s - max)
  const float SC = 0.25f * 1.4426950408889634f;
  const int r0 = tid, r1 = tid + 256;
  float4 qa[4], qb[4];
  #pragma unroll
  for (int i = 0; i < 4; ++i) {
    qa[i] = *(const float4*)&Aq[r0 * Dd + i * 4]; scl4(qa[i], SC);
    qb[i] = *(const float4*)&Aq[r1 * Dd + i * 4]; scl4(qb[i], SC);
  }
  __syncthreads();

  float mxa = -INFINITY, mxb = -INFINITY, la = 0.f, lb = 0.f;
  float4 oa[4], ob[4];
  #pragma unroll
  for (int i = 0; i < 4; ++i) {
    oa[i] = make_float4(0.f, 0.f, 0.f, 0.f);
    ob[i] = make_float4(0.f, 0.f, 0.f, 0.f);
  }

  for (int m0 = 0; m0 < Nn; m0 += 16) {
    float sa[16], sb[16];
    #pragma unroll
    for (int j = 0; j < 16; ++j) {
      const float* kp = &Ks_[(m0 + j) * Dd];      // broadcast read (all lanes same addr)
      float4 k0 = *(const float4*)(kp + 0);
      float4 k1 = *(const float4*)(kp + 4);
      float4 k2 = *(const float4*)(kp + 8);
      float4 k3 = *(const float4*)(kp + 12);
      float s = 0.f;
      s = dot4(qa[0], k0, s); s = dot4(qa[1], k1, s);
      s = dot4(qa[2], k2, s); s = dot4(qa[3], k3, s);
      sa[j] = s;
      s = 0.f;
      s = dot4(qb[0], k0, s); s = dot4(qb[1], k1, s);
      s = dot4(qb[2], k2, s); s = dot4(qb[3], k3, s);
      sb[j] = s;
    }
    // chunk max merge (amortized rescale: 1 per 16 columns, no divergence)
    float ca = sa[0], cb = sb[0];
    #pragma unroll
    for (int j = 1; j < 16; ++j) { ca = fmaxf(ca, sa[j]); cb = fmaxf(cb, sb[j]); }
    const float na = fmaxf(mxa, ca), nb = fmaxf(mxb, cb);
    const float fa = exp2f(mxa - na), fb = exp2f(mxb - nb);
    mxa = na; mxb = nb;
    la *= fa; lb *= fb;
    #pragma unroll
    for (int i = 0; i < 4; ++i) { scl4(oa[i], fa); scl4(ob[i], fb); }
    #pragma unroll
    for (int j = 0; j < 16; ++j) {
      const float pa = exp2f(sa[j] - mxa);
      const float pb = exp2f(sb[j] - mxb);
      la += pa; lb += pb;
      const float* vp = &Vs_[(m0 + j) * Dd];      // broadcast read
      float4 v0 = *(const float4*)(vp + 0);
      float4 v1 = *(const float4*)(vp + 4);
      float4 v2 = *(const float4*)(vp + 8);
      float4 v3 = *(const float4*)(vp + 12);
      fma4(oa[0], pa, v0); fma4(oa[1], pa, v1);
      fma4(oa[2], pa, v2); fma4(oa[3], pa, v3);
      fma4(ob[0], pb, v0); fma4(ob[1], pb, v1);
      fma4(ob[2], pb, v2); fma4(ob[3], pb, v3);
    }
  }

  const float inva = 1.0f / la, invb = 1.0f / lb;
  const int b = slice / (Hh * Tt);
  const int h = (slice / Tt) % Hh;
  const int t = slice % Tt;
  float* __restrict__ outp = ctx + (size_t)ty * PROJ;
  const size_t rowA = (((size_t)b * Nn + r0) * Tt + t) * Ee + h * Dd;
  const size_t rowB = (((size_t)b * Nn + r1) * Tt + t) * Ee + h * Dd;
  #pragma unroll
  for (int i = 0; i < 4; ++i) {
    float4 va = oa[i]; scl4(va, inva);
    float4 vb = ob[i]; scl4(vb, invb);
    *(float4*)&outp[rowA + i * 4] = va;
    *(float4*)&outp[rowB + i * 4] = vb;
  }
}

// ---------------------------------------------------------------------------
// Kernel O: out[ty] = ctx[ty] @ Wout + bout   (token-major in and out)
// ---------------------------------------------------------------------------
__global__ __launch_bounds__(256) void out_kernel(
    const float* __restrict__ ctx, const float* __restrict__ Wout,
    const float* __restrict__ bout, float* __restrict__ out)
{
  __shared__ float Ws[Ee * Ee];
  __shared__ float Xs[MT * Ee];
  const int ty  = blockIdx.y;
  const int tid = threadIdx.x;
  const float* __restrict__ x = ctx + (size_t)ty * PROJ;
  const int tk0 = blockIdx.x * MT;

  for (int i = tid * 4; i < Ee * Ee; i += 1024)
    *(float4*)&Ws[i] = *(const float4*)&Wout[i];
  for (int i = tid * 4; i < MT * Ee; i += 1024)
    *(float4*)&Xs[i] = *(const float4*)&x[(size_t)tk0 * Ee + i];
  __syncthreads();

  const int c4 = (tid & 31) * 4;
  const int tg = tid >> 5;

  float4 acc[4];
  #pragma unroll
  for (int i = 0; i < 4; ++i) acc[i] = make_float4(0.f, 0.f, 0.f, 0.f);

  for (int k = 0; k < Ee; k += 4) {
    float4 w0 = *(const float4*)&Ws[(k + 0) * Ee + c4];
    float4 w1 = *(const float4*)&Ws[(k + 1) * Ee + c4];
    float4 w2 = *(const float4*)&Ws[(k + 2) * Ee + c4];
    float4 w3 = *(const float4*)&Ws[(k + 3) * Ee + c4];
    #pragma unroll
    for (int tt = 0; tt < 4; ++tt) {
      float4 xv = *(const float4*)&Xs[(tg * 4 + tt) * Ee + k];
      fma4(acc[tt], xv.x, w0); fma4(acc[tt], xv.y, w1);
      fma4(acc[tt], xv.z, w2); fma4(acc[tt], xv.w, w3);
    }
  }

  const float4 bv = *(const float4*)&bout[c4];
  #pragma unroll
  for (int tt = 0; tt < 4; ++tt) {
    const int tk = tk0 + tg * 4 + tt;
    float4 r = acc[tt];
    r.x += bv.x; r.y += bv.y; r.z += bv.z; r.w += bv.w;
    *(float4*)&out[(size_t)ty * PROJ + (size_t)tk * Ee + c4] = r;
  }
}

// ---------------------------------------------------------------------------
extern "C" void kernel_launch(void* const* d_in, const int* in_sizes, int n_in,
                              void* d_out, int out_size, void* d_ws, size_t ws_size,
                              hipStream_t stream) {
  const float* fq  = (const float*)d_in[0];
  const float* fk  = (const float*)d_in[1];
  const float* fv  = (const float*)d_in[2];
  const float* sq  = (const float*)d_in[3];
  const float* sk  = (const float*)d_in[4];
  const float* sv  = (const float*)d_in[5];
  const float* WfQ = (const float*)d_in[6];
  const float* WfK = (const float*)d_in[7];
  const float* WfV = (const float*)d_in[8];
  const float* WsQ = (const float*)d_in[9];
  const float* WsK = (const float*)d_in[10];
  const float* WsV = (const float*)d_in[11];
  const float* Kj  = (const float*)d_in[12];
  const float* Vfp = (const float*)d_in[13];
  const float* Wout = (const float*)d_in[14];
  const float* bout = (const float*)d_in[15];

  float* proj = (float*)d_ws;                  // 7 * PROJ floats
  float* ctx  = proj + (size_t)7 * PROJ;       // 4 * PROJ floats

  PtrPack pp;
  pp.x[0] = fq; pp.x[1] = fk; pp.x[2] = fv;
  pp.x[3] = sq; pp.x[4] = sk; pp.x[5] = sv;
  pp.W[0] = WfQ; pp.W[1] = WfK; pp.W[2] = WfV;
  pp.W[3] = WsQ; pp.W[4] = WsK; pp.W[5] = WsV;

  proj_kernel<<<dim3(NTOK / MT, 6), 256, 0, stream>>>(pp, Kj, Vfp, proj);
  attn_kernel<<<dim3(SLICES, 4), 256, 0, stream>>>(proj, ctx);
  out_kernel<<<dim3(NTOK / MT, 4), 256, 0, stream>>>(ctx, Wout, bout, (float*)d_out);
}